// Round 1
// 835.435 us; speedup vs baseline: 1.1646x; 1.1646x over previous
//
#include <hip/hip_runtime.h>
#include <math.h>

typedef short bf16x8 __attribute__((ext_vector_type(8)));
typedef float f32x4 __attribute__((ext_vector_type(4)));
typedef float f32x2 __attribute__((ext_vector_type(2)));

__device__ __forceinline__ float bf2f(unsigned short u) {
    return __uint_as_float(((unsigned)u) << 16);
}
__device__ __forceinline__ unsigned short f2bf(float f) {
    unsigned u = __float_as_uint(f);
    unsigned r = u + 0x7FFF + ((u >> 16) & 1);   // RNE
    return (unsigned short)(r >> 16);
}
__device__ __forceinline__ unsigned char f2fp8(float f) {
    const int p = __builtin_amdgcn_cvt_pk_fp8_f32(f, f, 0, false);
    return (unsigned char)(p & 0xff);
}

#define GLD_LDS16(gp, lp)                                                     \
    __builtin_amdgcn_global_load_lds(                                         \
        (const __attribute__((address_space(1))) void*)(gp),                  \
        (__attribute__((address_space(3))) void*)(lp), 16, 0, 0)

// C[M,Ncols] = A[M,K](bf16) @ BT[Ncols,K](bf16)^T, fp32 acc via MFMA.
// OUTMODE: 0 = fp32, 1 = bf16, 2 = fp8 e4m3.
template <int BM, int BN, int OUTMODE>
__global__ __launch_bounds__(256) void gemm_mfma(const unsigned short* __restrict__ A,
                                                 const unsigned short* __restrict__ BT,
                                                 void* __restrict__ Cv,
                                                 int M, int Ncols, int K) {
    constexpr int WM = BM / 2, WN = BN / 2, TM = WM / 16, TN = WN / 16;
    __shared__ unsigned short Al[BM * 32];
    __shared__ unsigned short Bl[BN * 32];

    const int tid = threadIdx.x;
    const int w = tid >> 6, lane = tid & 63;
    const int wm = w >> 1, wn = w & 1;
    const int row0 = blockIdx.x * BM, col0 = blockIdx.y * BN;
    const int q = lane >> 4, r = lane & 15;

    f32x4 acc[TM][TN];
    #pragma unroll
    for (int mt = 0; mt < TM; ++mt)
        #pragma unroll
        for (int nt = 0; nt < TN; ++nt) {
            f32x4 z = {0.f, 0.f, 0.f, 0.f};
            acc[mt][nt] = z;
        }

    for (int k0 = 0; k0 < K; k0 += 32) {
        __syncthreads();
        // stage A tile: BM rows x 32 k (64 B/row = 4 x 16B chunks)
        #pragma unroll
        for (int i = 0; i < BM / 64; ++i) {
            const int idx = i * 256 + tid;
            const int arow = idx >> 2, ch = idx & 3;
            int grow = row0 + arow;
            if (grow >= M) grow = M - 1;
            GLD_LDS16(A + (size_t)grow * K + k0 + ch * 8,
                      Al + (size_t)(i * 256 + w * 64) * 8);
        }
        // stage BT tile: BN rows x 32 k
        #pragma unroll
        for (int i = 0; i < BN / 64; ++i) {
            const int idx = i * 256 + tid;
            const int brow = idx >> 2, ch = idx & 3;
            GLD_LDS16(BT + (size_t)(col0 + brow) * K + k0 + ch * 8,
                      Bl + (size_t)(i * 256 + w * 64) * 8);
        }
        asm volatile("s_waitcnt vmcnt(0)" ::: "memory");
        __syncthreads();

        bf16x8 af[TM], bfr[TN];
        #pragma unroll
        for (int mt = 0; mt < TM; ++mt)
            af[mt] = *(const bf16x8*)&Al[(wm * WM + mt * 16 + r) * 32 + q * 8];
        #pragma unroll
        for (int nt = 0; nt < TN; ++nt)
            bfr[nt] = *(const bf16x8*)&Bl[(wn * WN + nt * 16 + r) * 32 + q * 8];
        #pragma unroll
        for (int mt = 0; mt < TM; ++mt)
            #pragma unroll
            for (int nt = 0; nt < TN; ++nt)
                acc[mt][nt] = __builtin_amdgcn_mfma_f32_16x16x32_bf16(
                    af[mt], bfr[nt], acc[mt][nt], 0, 0, 0);
    }

    #pragma unroll
    for (int mt = 0; mt < TM; ++mt) {
        #pragma unroll
        for (int nt = 0; nt < TN; ++nt) {
            const int gcol = col0 + wn * WN + nt * 16 + r;
            #pragma unroll
            for (int j = 0; j < 4; ++j) {
                const int grow = row0 + wm * WM + mt * 16 + q * 4 + j;
                if (grow < M) {
                    if (OUTMODE == 2)
                        ((unsigned char*)Cv)[(size_t)grow * Ncols + gcol] = f2fp8(acc[mt][nt][j]);
                    else if (OUTMODE == 1)
                        ((unsigned short*)Cv)[(size_t)grow * Ncols + gcol] = f2bf(acc[mt][nt][j]);
                    else
                        ((float*)Cv)[(size_t)grow * Ncols + gcol] = acc[mt][nt][j];
                }
            }
        }
    }
}

__global__ __launch_bounds__(256) void cast_f32_bf16(const float* __restrict__ in,
                                                     unsigned short* __restrict__ out,
                                                     long n4) {
    const long i = ((long)blockIdx.x * 256 + threadIdx.x);
    if (i < n4) {
        const float4 v = ((const float4*)in)[i];
        ushort4 o;
        o.x = f2bf(v.x); o.y = f2bf(v.y); o.z = f2bf(v.z); o.w = f2bf(v.w);
        ((ushort4*)out)[i] = o;
    }
}

// in: K x N fp32 -> out: N x K bf16 (transpose + cast); small matrices only.
__global__ __launch_bounds__(256) void transpose_cast(const float* __restrict__ in,
                                                      unsigned short* __restrict__ out,
                                                      int K, int N) {
    const int idx = blockIdx.x * 256 + threadIdx.x;
    if (idx < K * N) {
        const int k = idx / N, n = idx % N;
        out[(size_t)n * K + k] = f2bf(in[idx]);
    }
}

// ---- CSR build via bucketed 2-pass counting sort ----
// bucket = row >> 8 (256 rows/bucket).  NBMAX covers N up to 131072.
#define NBMAX 512
#define SB_CH 4096   // edges per block in scatter_bucket (16/thread)

// LDS-privatized bucket histogram.
__global__ __launch_bounds__(256) void bucket_hist(const int* __restrict__ rows,
                                                   int* __restrict__ bcnt, int E) {
    __shared__ int h[NBMAX];
    for (int i = threadIdx.x; i < NBMAX; i += 256) h[i] = 0;
    __syncthreads();
    for (long i = (long)blockIdx.x * 256 + threadIdx.x; i < E; i += (long)gridDim.x * 256)
        atomicAdd(&h[rows[i] >> 8], 1);
    __syncthreads();
    for (int i = threadIdx.x; i < NBMAX; i += 256)
        if (h[i]) atomicAdd(&bcnt[i], h[i]);
}

// single-block exclusive scan of bucket counts -> bstart[0..nb], bstart[nb]=E
__global__ __launch_bounds__(512) void bucket_scan(const int* __restrict__ bcnt,
                                                   int* __restrict__ bstart, int nb) {
    __shared__ int s[NBMAX];
    const int t = threadIdx.x;
    const int v = (t < nb) ? bcnt[t] : 0;
    s[t] = v;
    __syncthreads();
    for (int o = 1; o < NBMAX; o <<= 1) {
        const int y = (t >= o) ? s[t - o] : 0;
        __syncthreads();
        s[t] += y;
        __syncthreads();
    }
    if (t < nb) bstart[t] = s[t] - v;
    if (t == nb - 1) bstart[nb] = s[t];
}

// scatter edges into bucket-grouped tmp. tmp[pos] = ((row&255)<<17 | col, val).
// Per-block LDS ranking + one global cursor reservation per (block,bucket):
// writes to each bucket form contiguous runs -> partial lines merge in L2.
__global__ __launch_bounds__(256) void scatter_bucket(const int* __restrict__ rows,
                                                      const int* __restrict__ cols,
                                                      const float* __restrict__ vals,
                                                      const int* __restrict__ bstart,
                                                      int* __restrict__ bcursor,
                                                      int2* __restrict__ tmp, int E) {
    __shared__ int lcnt[NBMAX];
    __shared__ int lbase[NBMAX];
    const int t = threadIdx.x;
    const long c0 = (long)blockIdx.x * SB_CH;
    for (int i = t; i < NBMAX; i += 256) lcnt[i] = 0;
    __syncthreads();
    int rank[16], b[16];
    #pragma unroll
    for (int i = 0; i < 16; ++i) {
        const long e = c0 + i * 256 + t;
        if (e < E) {
            b[i] = rows[e] >> 8;
            rank[i] = atomicAdd(&lcnt[b[i]], 1);
        }
    }
    __syncthreads();
    for (int i = t; i < NBMAX; i += 256)
        lbase[i] = lcnt[i] ? atomicAdd(&bcursor[i], lcnt[i]) : 0;
    __syncthreads();
    #pragma unroll
    for (int i = 0; i < 16; ++i) {
        const long e = c0 + i * 256 + t;
        if (e < E) {
            const int r = rows[e];
            const int pos = bstart[b[i]] + lbase[b[i]] + rank[i];
            tmp[pos] = make_int2(((r & 255) << 17) | cols[e], __float_as_int(vals[e]));
        }
    }
}

// one block per bucket: LDS row-histogram + scan -> rs[], then re-scatter into
// final CSR order.  Writes confined to one ~64KB window -> L2-merged.
__global__ __launch_bounds__(256) void bucket_to_csr(const int2* __restrict__ tmp,
                                                     const int* __restrict__ bstart,
                                                     int* __restrict__ rs,
                                                     int2* __restrict__ edges,
                                                     int N, int nb, int E) {
    __shared__ int rcnt[256];
    __shared__ int rsc[256];
    const int b = blockIdx.x;
    const int t = threadIdx.x;
    const int s = bstart[b], e = bstart[b + 1];
    rcnt[t] = 0;
    __syncthreads();
    for (int i = s + t; i < e; i += 256)
        atomicAdd(&rcnt[tmp[i].x >> 17], 1);
    __syncthreads();
    const int v = rcnt[t];
    rsc[t] = v;
    __syncthreads();
    for (int o = 1; o < 256; o <<= 1) {
        const int y = (t >= o) ? rsc[t - o] : 0;
        __syncthreads();
        rsc[t] += y;
        __syncthreads();
    }
    const int excl = rsc[t] - v;          // exclusive prefix within bucket
    const int grow = b * 256 + t;
    if (grow < N) rs[grow] = s + excl;
    if (b == nb - 1 && t == 0) rs[N] = E;
    __syncthreads();
    rcnt[t] = s + excl;                   // reuse as absolute cursor
    __syncthreads();
    for (int i = s + t; i < e; i += 256) {
        const int2 x = tmp[i];
        const int pos = atomicAdd(&rcnt[x.x >> 17], 1);
        edges[pos] = make_int2(x.x & 0x1FFFF, x.y);
    }
}

// ---- CSR spmm ----
// F=256 (fp8 X), fused bias+relu, bf16 out. Unroll x4 for MLP.
__global__ __launch_bounds__(256) void spmm_csr256_relu(const int2* __restrict__ edges,
                                                        const int* __restrict__ rs,
                                                        const unsigned char* __restrict__ X,
                                                        const float* __restrict__ bias,
                                                        unsigned short* __restrict__ Y, int N) {
    const int row = blockIdx.x * 4 + (threadIdx.x >> 6);
    if (row >= N) return;
    const int lane = threadIdx.x & 63;
    const int s = rs[row], e = rs[row + 1];
    float a0 = 0.f, a1 = 0.f, a2 = 0.f, a3 = 0.f;
    int i = s;
    for (; i + 3 < e; i += 4) {
        const int2 e0 = edges[i];
        const int2 e1 = edges[i + 1];
        const int2 e2 = edges[i + 2];
        const int2 e3 = edges[i + 3];
        const unsigned x0 = ((const unsigned*)(X + (size_t)e0.x * 256))[lane];
        const unsigned x1 = ((const unsigned*)(X + (size_t)e1.x * 256))[lane];
        const unsigned x2 = ((const unsigned*)(X + (size_t)e2.x * 256))[lane];
        const unsigned x3 = ((const unsigned*)(X + (size_t)e3.x * 256))[lane];
        const float v0 = __int_as_float(e0.y);
        const float v1 = __int_as_float(e1.y);
        const float v2 = __int_as_float(e2.y);
        const float v3 = __int_as_float(e3.y);
        const f32x2 l0 = __builtin_amdgcn_cvt_pk_f32_fp8(x0, false);
        const f32x2 h0 = __builtin_amdgcn_cvt_pk_f32_fp8(x0, true);
        const f32x2 l1 = __builtin_amdgcn_cvt_pk_f32_fp8(x1, false);
        const f32x2 h1 = __builtin_amdgcn_cvt_pk_f32_fp8(x1, true);
        const f32x2 l2 = __builtin_amdgcn_cvt_pk_f32_fp8(x2, false);
        const f32x2 h2 = __builtin_amdgcn_cvt_pk_f32_fp8(x2, true);
        const f32x2 l3 = __builtin_amdgcn_cvt_pk_f32_fp8(x3, false);
        const f32x2 h3 = __builtin_amdgcn_cvt_pk_f32_fp8(x3, true);
        a0 += v0 * l0.x + v1 * l1.x + v2 * l2.x + v3 * l3.x;
        a1 += v0 * l0.y + v1 * l1.y + v2 * l2.y + v3 * l3.y;
        a2 += v0 * h0.x + v1 * h1.x + v2 * h2.x + v3 * h3.x;
        a3 += v0 * h0.y + v1 * h1.y + v2 * h2.y + v3 * h3.y;
    }
    for (; i < e; ++i) {
        const int2 e0 = edges[i];
        const unsigned x0 = ((const unsigned*)(X + (size_t)e0.x * 256))[lane];
        const float v0 = __int_as_float(e0.y);
        const f32x2 l0 = __builtin_amdgcn_cvt_pk_f32_fp8(x0, false);
        const f32x2 h0 = __builtin_amdgcn_cvt_pk_f32_fp8(x0, true);
        a0 += v0 * l0.x;
        a1 += v0 * l0.y;
        a2 += v0 * h0.x;
        a3 += v0 * h0.y;
    }
    const float4 bb = ((const float4*)bias)[lane];
    ushort4 o;
    o.x = f2bf(fmaxf(a0 + bb.x, 0.f));
    o.y = f2bf(fmaxf(a1 + bb.y, 0.f));
    o.z = f2bf(fmaxf(a2 + bb.z, 0.f));
    o.w = f2bf(fmaxf(a3 + bb.w, 0.f));
    ((ushort4*)(Y + (size_t)row * 256))[lane] = o;
}

// F=64 (fp8 X), fused bias + log_softmax, fp32 out. Unroll x4.
__global__ __launch_bounds__(256) void spmm_csr64_lsm(const int2* __restrict__ edges,
                                                      const int* __restrict__ rs,
                                                      const unsigned char* __restrict__ X,
                                                      const float* __restrict__ bias,
                                                      float* __restrict__ out, int N) {
    const int row = blockIdx.x * 4 + (threadIdx.x >> 6);
    if (row >= N) return;
    const int lane = threadIdx.x & 63;
    const int s = rs[row], e = rs[row + 1];
    float acc = 0.f;
    int i = s;
    for (; i + 3 < e; i += 4) {
        const int2 e0 = edges[i];
        const int2 e1 = edges[i + 1];
        const int2 e2 = edges[i + 2];
        const int2 e3 = edges[i + 3];
        const int u0 = X[(size_t)e0.x * 64 + lane];
        const int u1 = X[(size_t)e1.x * 64 + lane];
        const int u2 = X[(size_t)e2.x * 64 + lane];
        const int u3 = X[(size_t)e3.x * 64 + lane];
        const float x0 = __builtin_amdgcn_cvt_f32_fp8(u0, 0);
        const float x1 = __builtin_amdgcn_cvt_f32_fp8(u1, 0);
        const float x2 = __builtin_amdgcn_cvt_f32_fp8(u2, 0);
        const float x3 = __builtin_amdgcn_cvt_f32_fp8(u3, 0);
        acc += __int_as_float(e0.y) * x0 + __int_as_float(e1.y) * x1
             + __int_as_float(e2.y) * x2 + __int_as_float(e3.y) * x3;
    }
    for (; i < e; ++i) {
        const int2 e0 = edges[i];
        const int u0 = X[(size_t)e0.x * 64 + lane];
        acc += __int_as_float(e0.y) * __builtin_amdgcn_cvt_f32_fp8(u0, 0);
    }
    float v = acc + bias[lane];
    float m = v;
    #pragma unroll
    for (int o = 32; o; o >>= 1) m = fmaxf(m, __shfl_xor(m, o));
    const float ex = __expf(v - m);
    float ssum = ex;
    #pragma unroll
    for (int o = 32; o; o >>= 1) ssum += __shfl_xor(ssum, o);
    out[(size_t)row * 64 + lane] = v - m - __logf(ssum);
}

extern "C" void kernel_launch(void* const* d_in, const int* in_sizes, int n_in,
                              void* d_out, int out_size, void* d_ws, size_t ws_size,
                              hipStream_t stream) {
    const float* x    = (const float*)d_in[0];
    const int*   erow = (const int*)d_in[1];
    const int*   ecol = (const int*)d_in[2];
    const float* eval = (const float*)d_in[3];
    const float* W1   = (const float*)d_in[4];
    const float* b1   = (const float*)d_in[5];
    const float* W2   = (const float*)d_in[6];
    const float* b2   = (const float*)d_in[7];
    float* out = (float*)d_out;

    const int E      = in_sizes[1];
    const int nhid   = in_sizes[5];              // 256
    const int nclass = in_sizes[7];              // 64
    const int nfeat  = in_sizes[4] / nhid;       // 512
    const int N      = in_sizes[0] / nfeat;      // 100000

    // workspace layout (~155 MB, aliased regions noted)
    char* w = (char*)d_ws;
    unsigned short* xb  = (unsigned short*)w;     // N*nfeat bf16 (102.4 MB)
    unsigned short* h1b = (unsigned short*)w;     // aliases xb after gemm1 (N*nhid bf16)
    int2* tmp = (int2*)w;                         // aliases xb during CSR build (E*8 <= 25.6 MB)
    w += (size_t)N * nfeat * 2;
    unsigned char* h0q = (unsigned char*)w;       // N*nhid fp8 (25.6 MB)
    unsigned char* h2q = h0q;                     // aliases h0q after spmm1 (N*nclass fp8)
    w += (size_t)N * nhid;
    int2* edges = (int2*)w;                       w += (size_t)E * 8;
    int* rs = (int*)w;                            w += (size_t)(N + 1) * 4;
    int* bcnt = (int*)w;                          w += NBMAX * 4;
    int* bcursor = (int*)w;                       w += NBMAX * 4;
    int* bstart = (int*)w;                        w += (NBMAX + 1) * 4;
    unsigned short* W1T = (unsigned short*)w;     w += (size_t)nfeat * nhid * 2;
    unsigned short* W2T = (unsigned short*)w;     w += (size_t)nhid * nclass * 2;

    const int nb = (N + 255) >> 8;                // 391 buckets of 256 rows

    // CSR build: bucketed 2-pass counting sort (shared by both spmm layers)
    hipMemsetAsync(bcnt, 0, (size_t)2 * NBMAX * sizeof(int), stream);  // bcnt + bcursor
    bucket_hist<<<512, 256, 0, stream>>>(erow, bcnt, E);
    bucket_scan<<<1, NBMAX, 0, stream>>>(bcnt, bstart, nb);
    scatter_bucket<<<(E + SB_CH - 1) / SB_CH, 256, 0, stream>>>(erow, ecol, eval, bstart,
                                                                bcursor, tmp, E);
    bucket_to_csr<<<nb, 256, 0, stream>>>(tmp, bstart, rs, edges, N, nb, E);

    // casts (xb write must follow bucket_to_csr's tmp reads; same stream => ordered)
    const long n4 = (long)N * nfeat / 4;
    cast_f32_bf16<<<(int)((n4 + 255) / 256), 256, 0, stream>>>(x, xb, n4);
    transpose_cast<<<(nfeat * nhid + 255) / 256, 256, 0, stream>>>(W1, W1T, nfeat, nhid);
    transpose_cast<<<(nhid * nclass + 255) / 256, 256, 0, stream>>>(W2, W2T, nhid, nclass);

    // layer 1: h0q = fp8(xb @ W1)  — BN=256 covers all of nhid, A read once
    dim3 g1((N + 127) / 128, nhid / 256);
    gemm_mfma<128, 256, 2><<<g1, 256, 0, stream>>>(xb, W1T, h0q, N, nhid, nfeat);
    // h1b = bf16(relu(spmm(h0q) + b1))
    spmm_csr256_relu<<<(N + 3) / 4, 256, 0, stream>>>(edges, rs, h0q, b1, h1b, N);

    // layer 2: h2q = fp8(h1b @ W2)
    dim3 g2((N + 127) / 128, nclass / 64);
    gemm_mfma<128, 64, 2><<<g2, 256, 0, stream>>>(h1b, W2T, h2q, N, nclass, nhid);
    // out = log_softmax(spmm(h2q) + b2)
    spmm_csr64_lsm<<<(N + 3) / 4, 256, 0, stream>>>(edges, rs, h2q, b2, out, N);
}